// Round 1
// baseline (136.287 us; speedup 1.0000x reference)
//
#include <hip/hip_runtime.h>

// DWT db4, 6 levels, zero mode. x:[64, 262144] f32 ->
// concat(cA6, cD6, cD5, cD4, cD3, cD2, cD1) flat.
//
// R4: single-wave blocks (NT=64, no s_barrier — __syncthreads in a 1-wave
// block is just a waitcnt), level 1 computed directly from global (4x
// float4 loads per group, L1/L2 serve the lane overlap) so there is no
// LDS staging pass. LDS holds only the level 2-6 ping-pong buffers
// (de-interleaved E/O, 7296 B). Detail stores are ownership-masked to
// [S_k*p, S_k*(p+1)) so neighbor-overlap writes and partial-line RMW are
// eliminated (owned starts are >=64 floats => 128B-aligned).
// Edge tiles p=0,127,128 use guarded scalar loads, same arithmetic.

#define NT 64
#define TT 32

#define N0 262144
#define M1 131075
#define M2 65541
#define M3 32774
#define M4 16390
#define M5 8198
#define M6 4102

#define LEN1 1210
#define LEN2 602
#define LEN3 298
#define LEN4 146
#define LEN5 70

#define NC1 303  // ceil(LEN1/4)
#define NC2 151
#define NC3 75
#define NC4 37
#define NC5 18

#define LO1 186  // detail ownership: store l in [LO_k, LO_k + S_k)
#define LO2 90
#define LO3 42
#define LO4 18
#define LO5 6

#define S1 1024
#define S2 512
#define S3 256
#define S4 128
#define S5 64

#define OFF_A6 ((size_t)0)
#define OFF_D6 ((size_t)262528)
#define OFF_D5 ((size_t)525056)
#define OFF_D4 ((size_t)1049728)
#define OFF_D3 ((size_t)2098688)
#define OFF_D2 ((size_t)4196224)
#define OFF_D1 ((size_t)8390848)

// LDS float layout (all float offsets 16B-aligned):
// B: E [0,608) O [608,1216)   (holds A1, then A3, then A5)
// C: E [1216,1520) O [1520,1824)  (holds A2, then A4)
#define BE 0
#define BO 608
#define CE 1216
#define CO 1520
#define LDS_FLOATS 1824

__device__ __constant__ float RLO[8] = {
    0.23037781330885523f, 0.7148465705525415f, 0.6308807679295904f,
    -0.02798376941698385f, -0.18703481171888114f, 0.030841381835986965f,
    0.032883011666982945f, -0.010597401784997278f};
__device__ __constant__ float RHI[8] = {
    -0.010597401784997278f, -0.032883011666982945f, 0.030841381835986965f,
    0.18703481171888114f, -0.02798376941698385f, -0.6308807679295904f,
    0.7148465705525415f, -0.23037781330885523f};

// Level-1 compute for one group of 4 outputs from 16 raw x values
// (window v[2..15], i.e. SHIFT=1 in e/o space). A -> LDS (de-interleaved),
// D -> global, ownership-masked.
__device__ __forceinline__ void l1_body(const float v[16], int c,
                                        float2* __restrict__ dE2,
                                        float2* __restrict__ dO2,
                                        float* __restrict__ dg, int hi) {
  float e[8] = {v[0], v[2], v[4], v[6], v[8], v[10], v[12], v[14]};
  float o[8] = {v[1], v[3], v[5], v[7], v[9], v[11], v[13], v[15]};
  float a[4], d[4];
#pragma unroll
  for (int j = 0; j < 4; ++j) {
    float aa = 0.f, dd = 0.f;
#pragma unroll
    for (int t = 0; t < 4; ++t) {
      float ev = e[j + t + 1];
      float ov = o[j + t + 1];
      aa = fmaf(RLO[2 * t], ev, aa);
      aa = fmaf(RLO[2 * t + 1], ov, aa);
      dd = fmaf(RHI[2 * t], ev, dd);
      dd = fmaf(RHI[2 * t + 1], ov, dd);
    }
    a[j] = aa;
    d[j] = dd;
  }
  dE2[c] = make_float2(a[0], a[2]);
  dO2[c] = make_float2(a[1], a[3]);
  const int l0 = 4 * c;
  if (l0 >= LO1 && l0 + 4 <= hi) {
#pragma unroll
    for (int j = 0; j < 4; ++j) __builtin_nontemporal_store(d[j], dg + l0 + j);
  } else {
#pragma unroll
    for (int j = 0; j < 4; ++j)
      if (l0 + j >= LO1 && l0 + j < hi)
        __builtin_nontemporal_store(d[j], dg + l0 + j);
  }
}

// Levels 2..5: LDS (E/O) -> LDS (E/O) + ownership-masked detail store.
template <int NC>
__device__ __forceinline__ void level_mid(const float4* __restrict__ sE4,
                                          const float4* __restrict__ sO4,
                                          float2* __restrict__ dE2,
                                          float2* __restrict__ dO2,
                                          float* __restrict__ dg, int lo,
                                          int hi) {
  for (int c = threadIdx.x; c < NC; c += NT) {
    float4 e0 = sE4[c], e1 = sE4[c + 1];
    float4 o0 = sO4[c], o1 = sO4[c + 1];
    float e[8] = {e0.x, e0.y, e0.z, e0.w, e1.x, e1.y, e1.z, e1.w};
    float o[8] = {o0.x, o0.y, o0.z, o0.w, o1.x, o1.y, o1.z, o1.w};
    float a[4], d[4];
#pragma unroll
    for (int j = 0; j < 4; ++j) {
      float aa = 0.f, dd = 0.f;
#pragma unroll
      for (int t = 0; t < 4; ++t) {
        float ev = e[j + t];
        float ov = o[j + t];
        aa = fmaf(RLO[2 * t], ev, aa);
        aa = fmaf(RLO[2 * t + 1], ov, aa);
        dd = fmaf(RHI[2 * t], ev, dd);
        dd = fmaf(RHI[2 * t + 1], ov, dd);
      }
      a[j] = aa;
      d[j] = dd;
    }
    dE2[c] = make_float2(a[0], a[2]);
    dO2[c] = make_float2(a[1], a[3]);
    const int l0 = 4 * c;
    if (l0 >= lo && l0 + 4 <= hi) {
#pragma unroll
      for (int j = 0; j < 4; ++j)
        __builtin_nontemporal_store(d[j], dg + l0 + j);
    } else {
#pragma unroll
      for (int j = 0; j < 4; ++j)
        if (l0 + j >= lo && l0 + j < hi)
          __builtin_nontemporal_store(d[j], dg + l0 + j);
    }
  }
}

__global__ __launch_bounds__(NT, 4) void dwt6_kernel(
    const float* __restrict__ x, float* __restrict__ out) {
  const int p = blockIdx.x;
  const int row = blockIdx.y;
  const int tid = threadIdx.x;

  __shared__ __align__(16) float lds[LDS_FLOATS];

  const int b6 = p * TT;
  const int b5 = 2 * b6 - 6;
  const int b4 = 2 * b5 - 6;
  const int b3 = 2 * b4 - 6;
  const int b2 = 2 * b3 - 6;
  const int b1 = 2 * b2 - 6;   // 1024p - 186
  const int sb = 2 * b1 - 8;   // 2048p - 380, multiple of 4 -> float4-aligned
  // interior blocks read x[sb .. sb + 8*(NC1-1) + 15] = [.., 2048p+2051];
  // p<=126 keeps that < N0 and sb>=0 needs p>=1.
  const bool edge = (p == 0) | (p >= 127);

  const float* __restrict__ xr = x + (size_t)row * N0;

  float2* bE2 = (float2*)(lds + BE);
  float2* bO2 = (float2*)(lds + BO);
  float2* cE2 = (float2*)(lds + CE);
  float2* cO2 = (float2*)(lds + CO);
  const float4* bE4 = (const float4*)(lds + BE);
  const float4* bO4 = (const float4*)(lds + BO);
  const float4* cE4 = (const float4*)(lds + CE);
  const float4* cO4 = (const float4*)(lds + CO);

  // ---------------- level 1: global -> LDS(B) + cD1 ----------------
  {
    float* __restrict__ dg = out + OFF_D1 + (size_t)row * M1 + b1;
    const int hi = min(LO1 + S1, M1 - b1);
    if (!edge) {
      const float4* __restrict__ x4 = (const float4*)(xr + sb);
      for (int c = tid; c < NC1; c += NT) {
        float4 q0 = x4[2 * c], q1 = x4[2 * c + 1];
        float4 q2 = x4[2 * c + 2], q3 = x4[2 * c + 3];
        float v[16] = {q0.x, q0.y, q0.z, q0.w, q1.x, q1.y, q1.z, q1.w,
                       q2.x, q2.y, q2.z, q2.w, q3.x, q3.y, q3.z, q3.w};
        l1_body(v, c, bE2, bO2, dg, hi);
      }
    } else {
      for (int c = tid; c < NC1; c += NT) {
        float v[16];
        const int base = sb + 8 * c;
#pragma unroll
        for (int k = 0; k < 16; ++k) {
          const int gi = base + k;
          v[k] = (gi >= 0 && gi < N0) ? xr[gi] : 0.f;
        }
        l1_body(v, c, bE2, bO2, dg, hi);
      }
    }
  }
  __syncthreads();

  // ---------------- levels 2..5 (B->C->B->C->B) ----------------
  level_mid<NC2>(bE4, bO4, cE2, cO2, out + OFF_D2 + (size_t)row * M2 + b2,
                 LO2, min(LO2 + S2, M2 - b2));
  __syncthreads();
  level_mid<NC3>(cE4, cO4, bE2, bO2, out + OFF_D3 + (size_t)row * M3 + b3,
                 LO3, min(LO3 + S3, M3 - b3));
  __syncthreads();
  level_mid<NC4>(bE4, bO4, cE2, cO2, out + OFF_D4 + (size_t)row * M4 + b4,
                 LO4, min(LO4 + S4, M4 - b4));
  __syncthreads();
  level_mid<NC5>(cE4, cO4, bE2, bO2, out + OFF_D5 + (size_t)row * M5 + b5,
                 LO5, min(LO5 + S5, M5 - b5));
  __syncthreads();

  // ---------------- level 6: LDS(B) -> cA6, cD6 ----------------
  {
    float* __restrict__ ga = out + OFF_A6 + (size_t)row * M6 + b6;
    float* __restrict__ gd = out + OFF_D6 + (size_t)row * M6 + b6;
    const int n6 = min(TT, M6 - b6);
    for (int c = tid; c < 8; c += NT) {
      float4 e0 = bE4[c], e1 = bE4[c + 1];
      float4 o0 = bO4[c], o1 = bO4[c + 1];
      float e[8] = {e0.x, e0.y, e0.z, e0.w, e1.x, e1.y, e1.z, e1.w};
      float o[8] = {o0.x, o0.y, o0.z, o0.w, o1.x, o1.y, o1.z, o1.w};
      const int l0 = 4 * c;
#pragma unroll
      for (int j = 0; j < 4; ++j) {
        float aa = 0.f, dd = 0.f;
#pragma unroll
        for (int t = 0; t < 4; ++t) {
          float ev = e[j + t];
          float ov = o[j + t];
          aa = fmaf(RLO[2 * t], ev, aa);
          aa = fmaf(RLO[2 * t + 1], ov, aa);
          dd = fmaf(RHI[2 * t], ev, dd);
          dd = fmaf(RHI[2 * t + 1], ov, dd);
        }
        if (l0 + j < n6) {
          __builtin_nontemporal_store(aa, ga + l0 + j);
          __builtin_nontemporal_store(dd, gd + l0 + j);
        }
      }
    }
  }
}

extern "C" void kernel_launch(void* const* d_in, const int* in_sizes, int n_in,
                              void* d_out, int out_size, void* d_ws,
                              size_t ws_size, hipStream_t stream) {
  const float* x = (const float*)d_in[0];
  float* out = (float*)d_out;
  dim3 grid(129, 64);  // 129 tiles of 32 level-6 outputs cover M6=4102
  dwt6_kernel<<<grid, NT, 0, stream>>>(x, out);
}

// Round 2
// 118.293 us; speedup vs baseline: 1.1521x; 1.1521x over previous
//
#include <hip/hip_runtime.h>

// DWT db4, 6 levels, zero mode. x:[64, 262144] f32 ->
// concat(cA6, cD6, cD5, cD4, cD3, cD2, cD1) flat.
//
// R5 = R3 skeleton (NT=256, TT=32, de-interleaved E/O LDS ping-pong,
// cooperative float4 staging, nt detail stores, unmasked halo writes)
// plus:
//  - 2 rows per block (grid 129x32): two independent chains per wave
//    (2x ILP/MLP between barriers), half the barriers per output.
//  - barrier-lite: s_waitcnt lgkmcnt(0) + s_barrier instead of
//    __syncthreads(), so in-flight nontemporal detail stores are NOT
//    drained at each of the 6 inter-level barriers (vmcnt stays
//    outstanding; staging loads are ordered by their ds_write data dep).

#define NT 256
#define TT 32

#define LEN0 2426
#define LEN1 1210
#define LEN2 602
#define LEN3 298
#define LEN4 146
#define LEN5 70

#define NC1 303
#define NC2 151
#define NC3 75
#define NC4 37
#define NC5 18

#define N0 262144
#define M1 131075
#define M2 65541
#define M3 32774
#define M4 16390
#define M5 8198
#define M6 4102

#define OFF_A6 ((size_t)0)
#define OFF_D6 ((size_t)262528)
#define OFF_D5 ((size_t)525056)
#define OFF_D4 ((size_t)1049728)
#define OFF_D3 ((size_t)2098688)
#define OFF_D2 ((size_t)4196224)
#define OFF_D1 ((size_t)8390848)

// per-row LDS float layout: A-E [0,1216) A-O [1216,2432) B-E [2432,3040)
// B-O [3040,3648). Row r at base r*RSTR. All offsets 16B-aligned.
#define AE 0
#define AO 1216
#define BE 2432
#define BO 3040
#define RSTR 3648
#define LDS_FLOATS (2 * RSTR)

__device__ __constant__ float RLO[8] = {
    0.23037781330885523f, 0.7148465705525415f, 0.6308807679295904f,
    -0.02798376941698385f, -0.18703481171888114f, 0.030841381835986965f,
    0.032883011666982945f, -0.010597401784997278f};
__device__ __constant__ float RHI[8] = {
    -0.010597401784997278f, -0.032883011666982945f, 0.030841381835986965f,
    0.18703481171888114f, -0.02798376941698385f, -0.6308807679295904f,
    0.7148465705525415f, -0.23037781330885523f};

// LDS-only barrier: order this wave's LDS ops, sync waves, but leave
// global (nontemporal detail) stores in flight across the barrier.
__device__ __forceinline__ void bar_lds() {
  asm volatile("s_waitcnt lgkmcnt(0)" ::: "memory");
  __builtin_amdgcn_s_barrier();
}

template <int SHIFT>
__device__ __forceinline__ void conv8(const float e[8], const float o[8],
                                      float a[4], float d[4]) {
#pragma unroll
  for (int j = 0; j < 4; ++j) {
    float aa = 0.f, dd = 0.f;
#pragma unroll
    for (int t = 0; t < 4; ++t) {
      float ev = e[j + t + SHIFT];
      float ov = o[j + t + SHIFT];
      aa = fmaf(RLO[2 * t], ev, aa);
      aa = fmaf(RLO[2 * t + 1], ov, aa);
      dd = fmaf(RHI[2 * t], ev, dd);
      dd = fmaf(RHI[2 * t + 1], ov, dd);
    }
    a[j] = aa;
    d[j] = dd;
  }
}

// One fast level for BOTH rows: src de-interleaved (E/O) at float offset
// sE/sO within each row's LDS region, dst at dE/dO, details -> global nt.
template <int LEN, int NC, int SHIFT>
__device__ __forceinline__ void level2r(float* __restrict__ R0,
                                        float* __restrict__ R1, int sE, int sO,
                                        int dE, int dO, float* __restrict__ dg0,
                                        float* __restrict__ dg1) {
  const float4* sE0 = (const float4*)(R0 + sE);
  const float4* sO0 = (const float4*)(R0 + sO);
  const float4* sE1 = (const float4*)(R1 + sE);
  const float4* sO1 = (const float4*)(R1 + sO);
  float2* dE0 = (float2*)(R0 + dE);
  float2* dO0 = (float2*)(R0 + dO);
  float2* dE1 = (float2*)(R1 + dE);
  float2* dO1 = (float2*)(R1 + dO);

  for (int c = threadIdx.x; c < NC; c += NT) {
    float4 ea0 = sE0[c], ea1 = sE0[c + 1];
    float4 oa0 = sO0[c], oa1 = sO0[c + 1];
    float4 eb0 = sE1[c], eb1 = sE1[c + 1];
    float4 ob0 = sO1[c], ob1 = sO1[c + 1];
    float e0[8] = {ea0.x, ea0.y, ea0.z, ea0.w, ea1.x, ea1.y, ea1.z, ea1.w};
    float o0[8] = {oa0.x, oa0.y, oa0.z, oa0.w, oa1.x, oa1.y, oa1.z, oa1.w};
    float e1[8] = {eb0.x, eb0.y, eb0.z, eb0.w, eb1.x, eb1.y, eb1.z, eb1.w};
    float o1[8] = {ob0.x, ob0.y, ob0.z, ob0.w, ob1.x, ob1.y, ob1.z, ob1.w};
    float a0[4], d0[4], a1[4], d1[4];
    conv8<SHIFT>(e0, o0, a0, d0);
    conv8<SHIFT>(e1, o1, a1, d1);
    dE0[c] = make_float2(a0[0], a0[2]);
    dO0[c] = make_float2(a0[1], a0[3]);
    dE1[c] = make_float2(a1[0], a1[2]);
    dO1[c] = make_float2(a1[1], a1[3]);
    const int l0 = 4 * c;
    if (l0 + 4 <= LEN) {
#pragma unroll
      for (int j = 0; j < 4; ++j) {
        __builtin_nontemporal_store(d0[j], dg0 + l0 + j);
        __builtin_nontemporal_store(d1[j], dg1 + l0 + j);
      }
    } else {
#pragma unroll
      for (int j = 0; j < 4; ++j)
        if (l0 + j < LEN) {
          __builtin_nontemporal_store(d0[j], dg0 + l0 + j);
          __builtin_nontemporal_store(d1[j], dg1 + l0 + j);
        }
    }
  }
}

// slow path (edge tiles): flat layout, bounds-checked, both rows
__device__ inline void dwt_step_slow2(const float* __restrict__ s0,
                                      const float* __restrict__ s1,
                                      float* __restrict__ d0,
                                      float* __restrict__ d1, int base, int len,
                                      int M, int cOff, float* __restrict__ dg0,
                                      float* __restrict__ dg1, int tid) {
  for (int l = tid; l < len; l += NT) {
    int g = base + l;
    float a0 = 0.f, t0 = 0.f, a1 = 0.f, t1 = 0.f;
    if (g >= 0 && g < M) {
#pragma unroll
      for (int m = 0; m < 8; ++m) {
        float v0 = s0[2 * l + m];
        float v1 = s1[2 * l + m];
        a0 = fmaf(RLO[m], v0, a0);
        t0 = fmaf(RHI[m], v0, t0);
        a1 = fmaf(RLO[m], v1, a1);
        t1 = fmaf(RHI[m], v1, t1);
      }
    }
    d0[l] = a0;
    d1[l] = a1;
    if (l >= cOff && g < M) {
      dg0[g] = t0;
      dg1[g] = t1;
    }
  }
}

__global__ __launch_bounds__(NT, 5) void dwt6_kernel(
    const float* __restrict__ x, float* __restrict__ out) {
  const int p = blockIdx.x;
  const int r0 = 2 * blockIdx.y;
  const int r1 = r0 + 1;
  const int tid = threadIdx.x;

  __shared__ __align__(16) float lds[LDS_FLOATS];
  float* __restrict__ L0 = lds;
  float* __restrict__ L1 = lds + RSTR;

  const int b6 = p * TT;
  const int b5 = 2 * b6 - 6;
  const int b4 = 2 * b5 - 6;
  const int b3 = 2 * b4 - 6;
  const int b2 = 2 * b3 - 6;
  const int b1 = 2 * b2 - 6;  // 1024p - 186
  const int b0 = 2 * b1 - 6;  // 2048p - 378

  const size_t ra1 = (size_t)r0 * M1, rb1 = (size_t)r1 * M1;
  const size_t ra2 = (size_t)r0 * M2, rb2 = (size_t)r1 * M2;
  const size_t ra3 = (size_t)r0 * M3, rb3 = (size_t)r1 * M3;
  const size_t ra4 = (size_t)r0 * M4, rb4 = (size_t)r1 * M4;
  const size_t ra5 = (size_t)r0 * M5, rb5 = (size_t)r1 * M5;
  const size_t ra6 = (size_t)r0 * M6, rb6 = (size_t)r1 * M6;

  if (p >= 1 && p <= 127) {
    // ---- fast path: all levels provably in-bounds ----
    // stage x[sb .. sb+2427], sb = b0-2 (multiple of 4) into A regions.
    const float4* __restrict__ xs0 =
        (const float4*)(x + (size_t)r0 * N0 + (b0 - 2));
    const float4* __restrict__ xs1 =
        (const float4*)(x + (size_t)r1 * N0 + (b0 - 2));
    float2* aE0 = (float2*)(L0 + AE);
    float2* aO0 = (float2*)(L0 + AO);
    float2* aE1 = (float2*)(L1 + AE);
    float2* aO1 = (float2*)(L1 + AO);
    for (int m = tid; m < 607; m += NT) {
      float4 v0 = xs0[m];
      float4 v1 = xs1[m];
      aE0[m] = make_float2(v0.x, v0.z);
      aO0[m] = make_float2(v0.y, v0.w);
      aE1[m] = make_float2(v1.x, v1.z);
      aO1[m] = make_float2(v1.y, v1.w);
    }
    bar_lds();

    level2r<LEN1, NC1, 1>(L0, L1, AE, AO, BE, BO, out + OFF_D1 + ra1 + b1,
                          out + OFF_D1 + rb1 + b1);
    bar_lds();
    level2r<LEN2, NC2, 0>(L0, L1, BE, BO, AE, AO, out + OFF_D2 + ra2 + b2,
                          out + OFF_D2 + rb2 + b2);
    bar_lds();
    level2r<LEN3, NC3, 0>(L0, L1, AE, AO, BE, BO, out + OFF_D3 + ra3 + b3,
                          out + OFF_D3 + rb3 + b3);
    bar_lds();
    level2r<LEN4, NC4, 0>(L0, L1, BE, BO, AE, AO, out + OFF_D4 + ra4 + b4,
                          out + OFF_D4 + rb4 + b4);
    bar_lds();
    level2r<LEN5, NC5, 0>(L0, L1, AE, AO, BE, BO, out + OFF_D5 + ra5 + b5,
                          out + OFF_D5 + rb5 + b5);
    bar_lds();

    // level 6: 32 outputs/row, straight to global
    const float4* bE0 = (const float4*)(L0 + BE);
    const float4* bO0 = (const float4*)(L0 + BO);
    const float4* bE1 = (const float4*)(L1 + BE);
    const float4* bO1 = (const float4*)(L1 + BO);
    float* __restrict__ ga0 = out + OFF_A6 + ra6 + b6;
    float* __restrict__ gd0 = out + OFF_D6 + ra6 + b6;
    float* __restrict__ ga1 = out + OFF_A6 + rb6 + b6;
    float* __restrict__ gd1 = out + OFF_D6 + rb6 + b6;
    for (int c = tid; c < 8; c += NT) {
      float4 ea0 = bE0[c], ea1 = bE0[c + 1];
      float4 oa0 = bO0[c], oa1 = bO0[c + 1];
      float4 eb0 = bE1[c], eb1 = bE1[c + 1];
      float4 ob0 = bO1[c], ob1 = bO1[c + 1];
      float e0[8] = {ea0.x, ea0.y, ea0.z, ea0.w, ea1.x, ea1.y, ea1.z, ea1.w};
      float o0[8] = {oa0.x, oa0.y, oa0.z, oa0.w, oa1.x, oa1.y, oa1.z, oa1.w};
      float e1[8] = {eb0.x, eb0.y, eb0.z, eb0.w, eb1.x, eb1.y, eb1.z, eb1.w};
      float o1[8] = {ob0.x, ob0.y, ob0.z, ob0.w, ob1.x, ob1.y, ob1.z, ob1.w};
      float a0[4], d0[4], a1[4], d1[4];
      conv8<0>(e0, o0, a0, d0);
      conv8<0>(e1, o1, a1, d1);
      const int l0 = 4 * c;
#pragma unroll
      for (int j = 0; j < 4; ++j) {
        __builtin_nontemporal_store(a0[j], ga0 + l0 + j);
        __builtin_nontemporal_store(d0[j], gd0 + l0 + j);
        __builtin_nontemporal_store(a1[j], ga1 + l0 + j);
        __builtin_nontemporal_store(d1[j], gd1 + l0 + j);
      }
    }
  } else {
    // ---- slow path: p == 0 or p == 128, both rows interleaved ----
    float* A0 = L0;        // LEN0 = 2426 <= 2432
    float* B0 = L0 + BE;   // LEN1 = 1210 <= 1216
    float* A1 = L1;
    float* B1 = L1 + BE;
    const float* __restrict__ xr0 = x + (size_t)r0 * N0;
    const float* __restrict__ xr1 = x + (size_t)r1 * N0;
    for (int l = tid; l < LEN0; l += NT) {
      int g = b0 + l;
      bool ok = (g >= 0 && g < N0);
      A0[l] = ok ? xr0[g] : 0.0f;
      A1[l] = ok ? xr1[g] : 0.0f;
    }
    bar_lds();

    dwt_step_slow2(A0, A1, B0, B1, b1, LEN1, M1, 186, out + OFF_D1 + ra1,
                   out + OFF_D1 + rb1, tid);
    bar_lds();
    dwt_step_slow2(B0, B1, A0, A1, b2, LEN2, M2, 90, out + OFF_D2 + ra2,
                   out + OFF_D2 + rb2, tid);
    bar_lds();
    dwt_step_slow2(A0, A1, B0, B1, b3, LEN3, M3, 42, out + OFF_D3 + ra3,
                   out + OFF_D3 + rb3, tid);
    bar_lds();
    dwt_step_slow2(B0, B1, A0, A1, b4, LEN4, M4, 18, out + OFF_D4 + ra4,
                   out + OFF_D4 + rb4, tid);
    bar_lds();
    dwt_step_slow2(A0, A1, B0, B1, b5, LEN5, M5, 6, out + OFF_D5 + ra5,
                   out + OFF_D5 + rb5, tid);
    bar_lds();

    for (int l = tid; l < TT; l += NT) {
      int g = b6 + l;
      if (g < M6) {
        float a0 = 0.f, d0 = 0.f, a1 = 0.f, d1 = 0.f;
#pragma unroll
        for (int m = 0; m < 8; ++m) {
          float v0 = B0[2 * l + m];
          float v1 = B1[2 * l + m];
          a0 = fmaf(RLO[m], v0, a0);
          d0 = fmaf(RHI[m], v0, d0);
          a1 = fmaf(RLO[m], v1, a1);
          d1 = fmaf(RHI[m], v1, d1);
        }
        out[OFF_A6 + ra6 + g] = a0;
        out[OFF_D6 + ra6 + g] = d0;
        out[OFF_A6 + rb6 + g] = a1;
        out[OFF_D6 + rb6 + g] = d1;
      }
    }
  }
}

extern "C" void kernel_launch(void* const* d_in, const int* in_sizes, int n_in,
                              void* d_out, int out_size, void* d_ws,
                              size_t ws_size, hipStream_t stream) {
  const float* x = (const float*)d_in[0];
  float* out = (float*)d_out;
  dim3 grid(129, 32);  // 129 tiles x 32 row-pairs
  dwt6_kernel<<<grid, NT, 0, stream>>>(x, out);
}

// Round 3
// 117.877 us; speedup vs baseline: 1.1562x; 1.0035x over previous
//
#include <hip/hip_runtime.h>

// DWT db4, 6 levels, zero mode. x:[64, 262144] f32 ->
// concat(cA6, cD6, cD5, cD4, cD3, cD2, cD1) flat.
//
// R6: TT=64 tiles, NT=512 (8 waves), LDS 26.9KB -> 4 blocks/CU = 32
// waves/CU (full residency, same as R3; protects the R5 lesson).
// Stages: stage -> L1 -> L2 -> L34(fused) -> L56(fused): 4 barriers
// instead of 6. Fused stages recompute small cA windows in registers
// (+~3% FLOPs) and skip the cA3/cA5 LDS round-trips. bar_lds barriers
// (lgkmcnt-only) keep detail nt-stores in flight across barriers.
// De-interleaved E/O layout, all LDS reads b128 / writes b64.

#define NT 512
#define TT 64

#define N0 262144
#define M1 131075
#define M2 65541
#define M3 32774
#define M4 16390
#define M5 8198
#define M6 4102

#define LEN0 4474
#define LEN1 2234
#define LEN2 1114
#define LEN3 554
#define LEN4 274
#define LEN5 134

#define NC1 559
#define NC2 279
#define NC3 139
#define NC4 69
#define NC5 34

#define OFF_A6 ((size_t)0)
#define OFF_D6 ((size_t)262528)
#define OFF_D5 ((size_t)525056)
#define OFF_D4 ((size_t)1049728)
#define OFF_D3 ((size_t)2098688)
#define OFF_D2 ((size_t)4196224)
#define OFF_D1 ((size_t)8390848)

// LDS float layout: A-E [0,2240) A-O [2240,4480) B-E [4480,5600) B-O [5600,6720)
#define AE 0
#define AO 2240
#define BE 4480
#define BO 5600
#define LDS_FLOATS 6720

__device__ __constant__ float RLO[8] = {
    0.23037781330885523f, 0.7148465705525415f, 0.6308807679295904f,
    -0.02798376941698385f, -0.18703481171888114f, 0.030841381835986965f,
    0.032883011666982945f, -0.010597401784997278f};
__device__ __constant__ float RHI[8] = {
    -0.010597401784997278f, -0.032883011666982945f, 0.030841381835986965f,
    0.18703481171888114f, -0.02798376941698385f, -0.6308807679295904f,
    0.7148465705525415f, -0.23037781330885523f};

// LDS-only barrier: order LDS ops, sync waves; global nt stores stay in
// flight (drained once at endpgm).
__device__ __forceinline__ void bar_lds() {
  asm volatile("s_waitcnt lgkmcnt(0)" ::: "memory");
  __builtin_amdgcn_s_barrier();
}

// One standard level: src de-interleaved (sE4/sO4), dst de-interleaved
// (dE2/dO2), details -> global nt. SHIFT=1 for level 1 (stage buffer
// starts 2 floats before the window base), 0 otherwise.
template <int LEN, int NC, int SHIFT>
__device__ __forceinline__ void level_fast(const float4* __restrict__ sE4,
                                           const float4* __restrict__ sO4,
                                           float2* __restrict__ dE2,
                                           float2* __restrict__ dO2,
                                           float* __restrict__ dg) {
  for (int c = threadIdx.x; c < NC; c += NT) {
    float4 e0 = sE4[c], e1 = sE4[c + 1];
    float4 o0 = sO4[c], o1 = sO4[c + 1];
    float e[8] = {e0.x, e0.y, e0.z, e0.w, e1.x, e1.y, e1.z, e1.w};
    float o[8] = {o0.x, o0.y, o0.z, o0.w, o1.x, o1.y, o1.z, o1.w};
    float a[4], d[4];
#pragma unroll
    for (int j = 0; j < 4; ++j) {
      float aa = 0.f, dd = 0.f;
#pragma unroll
      for (int t = 0; t < 4; ++t) {
        float ev = e[j + t + SHIFT];
        float ov = o[j + t + SHIFT];
        aa = fmaf(RLO[2 * t], ev, aa);
        aa = fmaf(RLO[2 * t + 1], ov, aa);
        dd = fmaf(RHI[2 * t], ev, dd);
        dd = fmaf(RHI[2 * t + 1], ov, dd);
      }
      a[j] = aa;
      d[j] = dd;
    }
    dE2[c] = make_float2(a[0], a[2]);
    dO2[c] = make_float2(a[1], a[3]);
    const int l0 = 4 * c;
    if (l0 + 4 <= LEN) {
#pragma unroll
      for (int j = 0; j < 4; ++j) __builtin_nontemporal_store(d[j], dg + l0 + j);
    } else {
#pragma unroll
      for (int j = 0; j < 4; ++j)
        if (l0 + j < LEN) __builtin_nontemporal_store(d[j], dg + l0 + j);
    }
  }
}

// slow path (edge tiles): flat layout, bounds-checked
__device__ inline void dwt_step_slow(const float* __restrict__ s,
                                     float* __restrict__ d, int base, int len,
                                     int M, int cOff, float* __restrict__ dglob,
                                     int tid) {
  for (int l = tid; l < len; l += NT) {
    int g = base + l;
    float a = 0.f, dt = 0.f;
    if (g >= 0 && g < M) {
#pragma unroll
      for (int m = 0; m < 8; ++m) {
        float v = s[2 * l + m];
        a = fmaf(RLO[m], v, a);
        dt = fmaf(RHI[m], v, dt);
      }
    }
    d[l] = a;
    if (l >= cOff && g < M) dglob[g] = dt;
  }
}

__global__ __launch_bounds__(NT, 8) void dwt6_kernel(
    const float* __restrict__ x, float* __restrict__ out) {
  const int p = blockIdx.x;
  const int row = blockIdx.y;
  const int tid = threadIdx.x;

  __shared__ __align__(16) float lds[LDS_FLOATS];

  const int b6 = p * TT;           // 64p
  const int b5 = 2 * b6 - 6;       // 128p - 6
  const int b4 = 2 * b5 - 6;       // 256p - 18
  const int b3 = 2 * b4 - 6;       // 512p - 42
  const int b2 = 2 * b3 - 6;       // 1024p - 90
  const int b1 = 2 * b2 - 6;       // 2048p - 186
  const int b0 = 2 * b1 - 6;       // 4096p - 378

  const size_t r1 = (size_t)row * M1, r2 = (size_t)row * M2,
               r3 = (size_t)row * M3, r4 = (size_t)row * M4,
               r5 = (size_t)row * M5, r6 = (size_t)row * M6;

  float2* aE2 = (float2*)(lds + AE);
  float2* aO2 = (float2*)(lds + AO);
  float2* bE2 = (float2*)(lds + BE);
  float2* bO2 = (float2*)(lds + BO);
  const float4* aE4 = (const float4*)(lds + AE);
  const float4* aO4 = (const float4*)(lds + AO);
  const float4* bE4 = (const float4*)(lds + BE);
  const float4* bO4 = (const float4*)(lds + BO);

  if (p >= 1 && p <= 63) {
    // ---- fast path: all levels provably in-bounds ----
    // stage x[sb .. sb+4475], sb = b0-2 (multiple of 4), de-interleaved.
    const float4* __restrict__ xs4 =
        (const float4*)(x + (size_t)row * N0 + (b0 - 2));
    for (int m = tid; m < 1119; m += NT) {
      float4 v = xs4[m];
      aE2[m] = make_float2(v.x, v.z);
      aO2[m] = make_float2(v.y, v.w);
    }
    bar_lds();

    level_fast<LEN1, NC1, 1>(aE4, aO4, bE2, bO2, out + OFF_D1 + r1 + b1);
    bar_lds();
    level_fast<LEN2, NC2, 0>(bE4, bO4, aE2, aO2, out + OFF_D2 + r2 + b2);
    bar_lds();

    // ---- L34 fused: read cA2 (A); write cA4 -> B; store cD3, cD4 ----
    {
      float* __restrict__ dg3 = out + OFF_D3 + r3 + b3;
      float* __restrict__ dg4 = out + OFF_D4 + r4 + b4;
      if (tid < NC4) {  // waves 0-1: cD4 + cA4 (recompute cA3 window)
        const int c = tid;
        float E[20], O[20];
#pragma unroll
        for (int q = 0; q < 5; ++q) {
          float4 ev = aE4[2 * c + q], ov = aO4[2 * c + q];
          E[4 * q] = ev.x; E[4 * q + 1] = ev.y;
          E[4 * q + 2] = ev.z; E[4 * q + 3] = ev.w;
          O[4 * q] = ov.x; O[4 * q + 1] = ov.y;
          O[4 * q + 2] = ov.z; O[4 * q + 3] = ov.w;
        }
        float c3[14];
#pragma unroll
        for (int k = 0; k < 14; ++k) {
          float s = 0.f;
#pragma unroll
          for (int t = 0; t < 4; ++t) {
            s = fmaf(RLO[2 * t], E[k + t], s);
            s = fmaf(RLO[2 * t + 1], O[k + t], s);
          }
          c3[k] = s;
        }
        float a4[4], d4[4];
#pragma unroll
        for (int j = 0; j < 4; ++j) {
          float aa = 0.f, dd = 0.f;
#pragma unroll
          for (int t = 0; t < 4; ++t) {
            aa = fmaf(RLO[2 * t], c3[2 * j + 2 * t], aa);
            aa = fmaf(RLO[2 * t + 1], c3[2 * j + 2 * t + 1], aa);
            dd = fmaf(RHI[2 * t], c3[2 * j + 2 * t], dd);
            dd = fmaf(RHI[2 * t + 1], c3[2 * j + 2 * t + 1], dd);
          }
          a4[j] = aa;
          d4[j] = dd;
        }
        bE2[c] = make_float2(a4[0], a4[2]);
        bO2[c] = make_float2(a4[1], a4[3]);
        const int l0 = 4 * c;
#pragma unroll
        for (int j = 0; j < 4; ++j)
          if (l0 + j < LEN4) __builtin_nontemporal_store(d4[j], dg4 + l0 + j);
      } else if (tid >= 128 && tid < 128 + NC3) {  // waves 2-4: cD3 direct
        const int c = tid - 128;
        float4 e0 = aE4[c], e1 = aE4[c + 1];
        float4 o0 = aO4[c], o1 = aO4[c + 1];
        float e[8] = {e0.x, e0.y, e0.z, e0.w, e1.x, e1.y, e1.z, e1.w};
        float o[8] = {o0.x, o0.y, o0.z, o0.w, o1.x, o1.y, o1.z, o1.w};
        const int l0 = 4 * c;
#pragma unroll
        for (int j = 0; j < 4; ++j) {
          float dd = 0.f;
#pragma unroll
          for (int t = 0; t < 4; ++t) {
            dd = fmaf(RHI[2 * t], e[j + t], dd);
            dd = fmaf(RHI[2 * t + 1], o[j + t], dd);
          }
          if (l0 + j < LEN3) __builtin_nontemporal_store(dd, dg3 + l0 + j);
        }
      }
    }
    bar_lds();

    // ---- L56 fused: read cA4 (B); store cD5, cA6, cD6 ----
    {
      float* __restrict__ ga = out + OFF_A6 + r6 + b6;
      float* __restrict__ gd = out + OFF_D6 + r6 + b6;
      float* __restrict__ dg5 = out + OFF_D5 + r5 + b5;
      if (tid < 32) {  // wave 0: one cA6/cD6 output pair per lane
        const int c = tid;
        float E[16], O[16];
#pragma unroll
        for (int q = 0; q < 4; ++q) {
          float4 ev = bE4[c + q], ov = bO4[c + q];
          E[4 * q] = ev.x; E[4 * q + 1] = ev.y;
          E[4 * q + 2] = ev.z; E[4 * q + 3] = ev.w;
          O[4 * q] = ov.x; O[4 * q + 1] = ov.y;
          O[4 * q + 2] = ov.z; O[4 * q + 3] = ov.w;
        }
        float a5[10];
#pragma unroll
        for (int s = 0; s < 10; ++s) {
          float aa = 0.f;
#pragma unroll
          for (int t = 0; t < 4; ++t) {
            aa = fmaf(RLO[2 * t], E[s + t], aa);
            aa = fmaf(RLO[2 * t + 1], O[s + t], aa);
          }
          a5[s] = aa;
        }
#pragma unroll
        for (int j = 0; j < 2; ++j) {
          float aa = 0.f, dd = 0.f;
#pragma unroll
          for (int t = 0; t < 4; ++t) {
            aa = fmaf(RLO[2 * t], a5[2 * j + 2 * t], aa);
            aa = fmaf(RLO[2 * t + 1], a5[2 * j + 2 * t + 1], aa);
            dd = fmaf(RHI[2 * t], a5[2 * j + 2 * t], dd);
            dd = fmaf(RHI[2 * t + 1], a5[2 * j + 2 * t + 1], dd);
          }
          __builtin_nontemporal_store(aa, ga + 2 * c + j);
          __builtin_nontemporal_store(dd, gd + 2 * c + j);
        }
      } else if (tid >= 64 && tid < 64 + NC5) {  // wave 1: cD5 direct
        const int c = tid - 64;
        float4 e0 = bE4[c], e1 = bE4[c + 1];
        float4 o0 = bO4[c], o1 = bO4[c + 1];
        float e[8] = {e0.x, e0.y, e0.z, e0.w, e1.x, e1.y, e1.z, e1.w};
        float o[8] = {o0.x, o0.y, o0.z, o0.w, o1.x, o1.y, o1.z, o1.w};
        const int l0 = 4 * c;
#pragma unroll
        for (int j = 0; j < 4; ++j) {
          float dd = 0.f;
#pragma unroll
          for (int t = 0; t < 4; ++t) {
            dd = fmaf(RHI[2 * t], e[j + t], dd);
            dd = fmaf(RHI[2 * t + 1], o[j + t], dd);
          }
          if (l0 + j < LEN5) __builtin_nontemporal_store(dd, dg5 + l0 + j);
        }
      }
    }
  } else {
    // ---- slow path: p == 0 or p == 64 ----
    float* A = lds;          // LEN0 = 4474 <= 4480
    float* B = lds + BE;     // LEN1 = 2234 <= 2240
    const float* __restrict__ xr = x + (size_t)row * N0;
    for (int l = tid; l < LEN0; l += NT) {
      int g = b0 + l;
      A[l] = (g >= 0 && g < N0) ? xr[g] : 0.0f;
    }
    bar_lds();

    dwt_step_slow(A, B, b1, LEN1, M1, 186, out + OFF_D1 + r1, tid);
    bar_lds();
    dwt_step_slow(B, A, b2, LEN2, M2, 90, out + OFF_D2 + r2, tid);
    bar_lds();
    dwt_step_slow(A, B, b3, LEN3, M3, 42, out + OFF_D3 + r3, tid);
    bar_lds();
    dwt_step_slow(B, A, b4, LEN4, M4, 18, out + OFF_D4 + r4, tid);
    bar_lds();
    dwt_step_slow(A, B, b5, LEN5, M5, 6, out + OFF_D5 + r5, tid);
    bar_lds();

    for (int l = tid; l < TT; l += NT) {
      int g = b6 + l;
      if (g < M6) {
        float a = 0.f, dt = 0.f;
#pragma unroll
        for (int m = 0; m < 8; ++m) {
          float v = B[2 * l + m];
          a = fmaf(RLO[m], v, a);
          dt = fmaf(RHI[m], v, dt);
        }
        out[OFF_A6 + r6 + g] = a;
        out[OFF_D6 + r6 + g] = dt;
      }
    }
  }
}

extern "C" void kernel_launch(void* const* d_in, const int* in_sizes, int n_in,
                              void* d_out, int out_size, void* d_ws,
                              size_t ws_size, hipStream_t stream) {
  const float* x = (const float*)d_in[0];
  float* out = (float*)d_out;
  dim3 grid(65, 64);  // 65 tiles of 64 level-6 outputs cover M6=4102
  dwt6_kernel<<<grid, NT, 0, stream>>>(x, out);
}